// Round 18
// baseline (233.366 us; speedup 1.0000x reference)
//
#include <hip/hip_runtime.h>
#include <hip/hip_bf16.h>

// Problem constants
#define B_  16
#define T_  1024
#define C_  1024
#define H_  16
#define KW_ 31
#define M_  (B_ * T_)     // 16384 rows
#define N1_ (2 * C_)      // 2048  (GEMM1 N)
#define K1_ C_            // 1024  (GEMM1 K)
#define N2_ C_            // 1024  (GEMM2 N)
#define K2_ (2 * C_)      // 2048  (GEMM2 K)

typedef __attribute__((ext_vector_type(8))) short bf16x8;
typedef __attribute__((ext_vector_type(4))) short s16x4;
typedef __attribute__((ext_vector_type(16))) float f32x16;

typedef const __attribute__((address_space(1))) void GV;
typedef __attribute__((address_space(3))) void LV;

__device__ __forceinline__ short f2bf(float f) {
  union { float f; unsigned u; } v; v.f = f;
  unsigned r = v.u + 0x7fffu + ((v.u >> 16) & 1u);   // RNE
  return (short)(r >> 16);
}
__device__ __forceinline__ float b2f(short s) {
  union { float f; unsigned u; } v;
  v.u = ((unsigned)(unsigned short)s) << 16;
  return v.f;
}

// ---------------------------------------------------------------------------
// ONE prep launch, block-range partitioned; fold (longest pole) first.
__global__ __launch_bounds__(256) void prep_all(const float* __restrict__ q,
                                                const float* __restrict__ W1,
                                                const float* __restrict__ W2,
                                                const float* __restrict__ wtf,
                                                short* __restrict__ Abf,
                                                short* __restrict__ W1b,
                                                short* __restrict__ W2b) {
  const int bid = blockIdx.x;
  const int tid = threadIdx.x;
  if (bid < 4096) {
    // fold: W2fold[o,j] = sum_k wf[k] * W2[o, 1024 + (j+15-k)]
    int idx = bid * 256 + tid;                    // over 1048576
    int o = idx >> 10, j = idx & 1023;
    float e[KW_], mx = -1e30f, ssum = 0.f;
    #pragma unroll
    for (int k = 0; k < KW_; ++k) mx = fmaxf(mx, wtf[k]);
    #pragma unroll
    for (int k = 0; k < KW_; ++k) { e[k] = __expf(wtf[k] - mx); ssum += e[k]; }
    const float inv = 1.f / ssum;
    const float* base = W2 + (long)o * K2_ + C_;
    float s = 0.f;
    #pragma unroll
    for (int k = 0; k < KW_; ++k) {
      int c = j + 15 - k;
      if (c >= 0 && c < C_) s += e[k] * inv * base[c];
    }
    W2b[(long)o * K2_ + C_ + j] = f2bf(s);
  } else if (bid < 12288) {
    // cvt q: 2M threads x 8 elems
    int idx = (bid - 4096) * 256 + tid;
    const float4* src = (const float4*)q + (long)idx * 2;
    float4 f0 = src[0], f1 = src[1];
    bf16x8 o = { f2bf(f0.x), f2bf(f0.y), f2bf(f0.z), f2bf(f0.w),
                 f2bf(f1.x), f2bf(f1.y), f2bf(f1.z), f2bf(f1.w) };
    *((bf16x8*)Abf + idx) = o;
  } else if (bid < 13312) {
    // W1 interleave: row 2j = W1[j] (a), row 2j+1 = W1[1024+j] (g)
    int idx = (bid - 12288) * 256 + tid;          // over 262144
    int r = idx >> 7;
    int c = (idx & 127) * 8;
    int s = (r & 1) ? (1024 + (r >> 1)) : (r >> 1);
    const float* src = W1 + (long)s * 1024 + c;
    bf16x8 o;
    #pragma unroll
    for (int i = 0; i < 8; ++i) o[i] = f2bf(src[i]);
    *(bf16x8*)(W1b + (long)r * 1024 + c) = o;
  } else {
    // W2 first half copy
    int idx = (bid - 13312) * 256 + tid;          // over 131072
    int o  = idx >> 7;
    int c8 = (idx & 127) * 8;
    const float* src = W2 + (long)o * K2_ + c8;
    bf16x8 v;
    #pragma unroll
    for (int i = 0; i < 8; ++i) v[i] = f2bf(src[i]);
    *(bf16x8*)(W2b + (long)o * K2_ + c8) = v;
  }
}

// ---------------------------------------------------------------------------
// depthwise conv over time: xc[b,t,c] = sum_k w[c%16,k] * x[b,t+k-15,c]
// t-block = 64 -> 1024 blocks (4/CU, 16 waves/CU). Read amp 1.47x.
__global__ __launch_bounds__(256) void conv_t_k(const short* __restrict__ A2in,
                                                const float* __restrict__ wt,
                                                short* __restrict__ A2out) {
  const int tid = threadIdx.x;
  const int t0  = blockIdx.x * 64;
  const int c   = blockIdx.y * 256 + tid;
  const int b   = blockIdx.z;
  const int h   = c & (H_ - 1);

  float wk[KW_];
  {
    const float* src = wt + h * KW_;
    float mx = -1e30f, ssum = 0.f;
    #pragma unroll
    for (int k = 0; k < KW_; ++k) mx = fmaxf(mx, src[k]);
    #pragma unroll
    for (int k = 0; k < KW_; ++k) { wk[k] = __expf(src[k] - mx); ssum += wk[k]; }
    const float inv = 1.f / ssum;
    #pragma unroll
    for (int k = 0; k < KW_; ++k) wk[k] *= inv;
  }

  const long rowbase = ((long)b * T_) * K2_ + C_ + c;
  float win[KW_];
  #pragma unroll
  for (int k = 0; k < 30; ++k) {
    int t = t0 - 15 + k;
    win[k] = (t >= 0 && t < T_) ? b2f(A2in[rowbase + (long)t * K2_]) : 0.f;
  }
  for (int tt = 0; tt < 64; ++tt) {
    int tl = t0 + tt + 15;
    win[30] = (tl < T_) ? b2f(A2in[rowbase + (long)tl * K2_]) : 0.f;
    float s = 0.f;
    #pragma unroll
    for (int k = 0; k < KW_; ++k) s = fmaf(wk[k], win[k], s);
    A2out[((long)b * T_ + t0 + tt) * K2_ + c] = f2bf(s);
    #pragma unroll
    for (int k = 0; k < 30; ++k) win[k] = win[k + 1];
  }
}

// ---------------------------------------------------------------------------
// 256x128 bf16 GEMM, 32x32x16 MFMA, ring-of-3, HIGH intensity (32.8 read-
// FLOP/LDS-byte vs r9's 21.8) on r9's PROVEN bank geometry (BK=64 = 128B
// rows + XOR (r&7)<<4). This is r14's structure (layouts/ring HW-verified,
// absmax-clean) with its 64B-row 2x bank conflict removed.
// 8 waves (4M x 2N), per-wave 64x64 = 2mb x 2nb x 4kc MFMA. acc 2x2 f32x16
// = 64 AGPR + frags 64 VGPR -> ~150 regs, launch_bounds(512,2), 1 block/CU
// (144KB LDS = 3 bufs x (A 32KB + B 16KB)).
// Bank math (128B rows): every row starts at bank 0; XOR maps chunk ch ->
// ch^(r&7); a 32-row b128 frag read puts 4 lo-half + 4 hi-half lanes on
// each 16B slot = 8 accesses/bank = wave floor -> conflict-free.
// Phase t: {16 ds_read buf[t%3]; stage tile t+2 -> buf[(t+2)%3] (6 loads);
// VMW(6); lgkm(0); bar; setprio1; 16 MFMA; setprio0}.
// Ring audit: stage target holds tile t-1 (last read phase t-1, drained by
// t-1's lgkm(0) before its barrier; stage issues after crossing it). VMW(6):
// outstanding = t+1's 6 + t+2's 6 = 12 -> retires tile t+1; barrier follows
// -> phase t+1's reads cross-wave safe. Prologue ST(0),ST(1),VMW(6),bar.
// Tail: t=nt-2 VMW(0) (retire last tile), t=nt-1 bare lgkm-wall.
// LDS-floor estimate: (1536 read + 375 write) cyc per 4.2 MFLOP per CU
// -> ~2200 FLOP/cyc/CU -> ~51us/GEMM + overheads.

// stage the 32KB A region (4 loads/thread), linear dest + inv-swz source
#define ST_A(SB, KT) do { \
    _Pragma("unroll") \
    for (int i = 0; i < 4; ++i) { \
      int d = i * 8192 + tid * 16; \
      int r = d >> 7; \
      int scb = (d & 127) ^ ((r & 7) << 4); \
      __builtin_amdgcn_global_load_lds( \
        (GV*)(A + (long)(arow0 + r) * K + (KT) * 64 + (scb >> 1)), \
        (LV*)&lds[(SB) + (d >> 1)], 16, 0, 0); \
    } \
  } while (0)
// stage the 16KB B region (2 loads/thread)
#define ST_B(SB, KT) do { \
    _Pragma("unroll") \
    for (int i = 0; i < 2; ++i) { \
      int d = i * 8192 + tid * 16; \
      int r = d >> 7; \
      int scb = (d & 127) ^ ((r & 7) << 4); \
      __builtin_amdgcn_global_load_lds( \
        (GV*)(Bw + (long)(brow0 + r) * K + (KT) * 64 + (scb >> 1)), \
        (LV*)&lds[(SB) + 16384 + (d >> 1)], 16, 0, 0); \
    } \
  } while (0)

// read A frags: mb in {0,1}, kc in {0..3}; 32x32x16 operand (r14-verified):
// row = lane&31, k = (lane>>5)*8 + j  -> byte col = kc*32 + lhi*16
#define RD_A(RB) do { \
    _Pragma("unroll") \
    for (int mb = 0; mb < 2; ++mb) \
      _Pragma("unroll") \
      for (int kc = 0; kc < 4; ++kc) { \
        int r = wm * 64 + mb * 32 + l31; \
        int byt = (r * 128 + kc * 32 + lhi * 16) ^ ((r & 7) << 4); \
        aF[mb * 4 + kc] = *(const bf16x8*)&lds[(RB) + (byt >> 1)]; \
      } \
  } while (0)
#define RD_B(RB) do { \
    _Pragma("unroll") \
    for (int nb = 0; nb < 2; ++nb) \
      _Pragma("unroll") \
      for (int kc = 0; kc < 4; ++kc) { \
        int r = wn * 64 + nb * 32 + l31; \
        int byt = (r * 128 + kc * 32 + lhi * 16) ^ ((r & 7) << 4); \
        bF[nb * 4 + kc] = *(const bf16x8*)&lds[(RB) + 16384 + (byt >> 1)]; \
      } \
  } while (0)

// 16 MFMA (32x32x16): 2 mb x 2 nb x 4 kc
#define MM16() do { \
    _Pragma("unroll") \
    for (int mb = 0; mb < 2; ++mb) \
      _Pragma("unroll") \
      for (int nb = 0; nb < 2; ++nb) \
        _Pragma("unroll") \
        for (int kc = 0; kc < 4; ++kc) \
          acc[mb][nb] = __builtin_amdgcn_mfma_f32_32x32x16_bf16( \
              aF[mb * 4 + kc], bF[nb * 4 + kc], acc[mb][nb], 0, 0, 0); \
  } while (0)

#define VMW(n_)  asm volatile("s_waitcnt vmcnt(" #n_ ")" ::: "memory")
#define WALLBAR() do { asm volatile("s_waitcnt lgkmcnt(0)" ::: "memory"); \
                       asm volatile("" ::: "memory"); __builtin_amdgcn_s_barrier(); \
                       __builtin_amdgcn_s_setprio(1); } while (0)
#define PRIO0() __builtin_amdgcn_s_setprio(0)
#define RING_ADV(x) do { (x) += 24576; if ((x) == 73728) (x) = 0; } while (0)

template<int MODE>
__global__ __launch_bounds__(512, 2) void gemm_hi(const short* __restrict__ A,
                                                  const short* __restrict__ Bw,
                                                  const float* __restrict__ bias,
                                                  void* __restrict__ Cout,
                                                  int K, int NBN, int ldo) {
  __shared__ short lds[73728];   // 144 KB: 3 bufs x (A 32KB + B 16KB)
  const int tid  = threadIdx.x;
  const int lane = tid & 63;
  const int wave = tid >> 6;     // 0..7
  const int wm = wave >> 1, wn = wave & 1;   // 4M x 2N

  // bijective XCD swizzle (nwg % 8 == 0 for both GEMMs)
  const int nwg = gridDim.x;
  const int wg  = (blockIdx.x & 7) * (nwg >> 3) + (blockIdx.x >> 3);
  const int bm = wg / NBN, bn = wg % NBN;
  const int arow0 = bm * 256, brow0 = bn * 128;

  const int l31 = lane & 31;
  const int lhi = lane >> 5;

  f32x16 acc[2][2] = {};                 // 64 regs, per-wave 64x64 output
  const int nt = K >> 6;                 // 64-K tiles (>= 4)

  bf16x8 aF[8], bF[8];

  // prologue: tiles 0 (buf0) and 1 (buf1), 12 loads; retire tile0's 6.
  ST_A(0, 0); ST_B(0, 0);
  ST_A(24576, 1); ST_B(24576, 1);
  VMW(6);
  asm volatile("" ::: "memory"); __builtin_amdgcn_s_barrier();

  int rb = 0, sb = 49152;
  for (int t = 0; t + 2 < nt; ++t) {
    RD_A(rb); RD_B(rb);
    ST_A(sb, t + 2); ST_B(sb, t + 2);
    VMW(6);
    WALLBAR(); MM16(); PRIO0();
    RING_ADV(rb); RING_ADV(sb);
  }
  // t = nt-2: no stage; retire the last tile's loads too
  RD_A(rb); RD_B(rb);
  VMW(0);
  WALLBAR(); MM16(); PRIO0();
  RING_ADV(rb);
  // t = nt-1: fully resident
  RD_A(rb); RD_B(rb);
  asm volatile("s_waitcnt lgkmcnt(0)" ::: "memory");
  __builtin_amdgcn_s_setprio(1);
  MM16();
  __builtin_amdgcn_s_setprio(0);

  // epilogue: 32x32 C/D layout col = lane&31, row = (reg&3)+8*(reg>>2)+4*lhi
  #pragma unroll
  for (int mb = 0; mb < 2; ++mb) {
    #pragma unroll
    for (int nb = 0; nb < 2; ++nb) {
      const int c = brow0 + wn * 64 + nb * 32 + l31;
      #pragma unroll
      for (int reg = 0; reg < 16; ++reg) {
        const int r = arow0 + wm * 64 + mb * 32 + (reg & 3) + 8 * (reg >> 2) + 4 * lhi;
        float v = acc[mb][nb][reg];
        if (MODE == 0) {
          ((float*)Cout)[(long)r * ldo + c] = v + bias[c];
        } else {
          // interleaved: even c = a_{c/2}, odd c = g_{c/2}; GLU = a*sigmoid(g)
          const int oc = (c & 1) ? (1024 + (c >> 1)) : (c >> 1);
          v += bias[oc];
          float o = __shfl_xor(v, 1);    // partner lane holds the paired col
          if (!(c & 1))
            ((short*)Cout)[(long)r * ldo + 1024 + (c >> 1)] =
                f2bf(v / (1.f + __expf(-o)));
        }
      }
    }
  }
}

// ---------------------------------------------------------------------------
extern "C" void kernel_launch(void* const* d_in, const int* in_sizes, int n_in,
                              void* d_out, int out_size, void* d_ws, size_t ws_size,
                              hipStream_t stream) {
  const float* q   = (const float*)d_in[0];
  const float* W1  = (const float*)d_in[4];
  const float* b1  = (const float*)d_in[5];
  const float* W2  = (const float*)d_in[6];
  const float* b2  = (const float*)d_in[7];
  const float* wt  = (const float*)d_in[8];
  const float* wtf = (const float*)d_in[9];

  // workspace layout (bf16 as short), ~104 MB total
  short* Abf = (short*)d_ws;                       // 16384x1024
  short* W1b = Abf + (long)M_ * K1_;               // 2048x1024 interleaved
  short* W2b = W1b + (long)N1_ * K1_;              // 1024x2048 (B^T for GEMM2)
  short* A2  = W2b + (long)N2_ * K2_;              // 16384x2048: [xc | x]

  // one prep launch: fold W2 (longest pole, first) + cvt q + cvt W1 + cvt W2
  prep_all<<<13824, 256, 0, stream>>>(q, W1, W2, wtf, Abf, W1b, W2b);

  // GEMM1 + fused GLU: x -> A2[:, 1024:2048]
  gemm_hi<1><<<(M_ / 256) * (N1_ / 128), 512, 0, stream>>>(
      Abf, W1b, b1, A2, K1_, N1_ / 128, K2_);

  // time depthwise conv (inline per-head softmax) -> A2[:, 0:1024]
  conv_t_k<<<dim3(T_ / 64, C_ / 256, B_), 256, 0, stream>>>(A2, wt, A2);

  // GEMM2: out = A2 @ W2b^T + b2 -> fp32
  gemm_hi<0><<<(M_ / 256) * (N2_ / 128), 512, 0, stream>>>(
      A2, W2b, b2, d_out, K2_, N2_ / 128, N2_);
}

// Round 19
// 209.524 us; speedup vs baseline: 1.1138x; 1.1138x over previous
//
#include <hip/hip_runtime.h>
#include <hip/hip_bf16.h>

// Problem constants
#define B_  16
#define T_  1024
#define C_  1024
#define H_  16
#define KW_ 31
#define M_  (B_ * T_)     // 16384 rows
#define N1_ (2 * C_)      // 2048  (GEMM1 N)
#define K1_ C_            // 1024  (GEMM1 K)
#define N2_ C_            // 1024  (GEMM2 N)
#define K2_ (2 * C_)      // 2048  (GEMM2 K)

typedef __attribute__((ext_vector_type(8))) short bf16x8;
typedef __attribute__((ext_vector_type(4))) short s16x4;
typedef __attribute__((ext_vector_type(4))) float f32x4;

typedef const __attribute__((address_space(1))) void GV;
typedef __attribute__((address_space(3))) void LV;

__device__ __forceinline__ short f2bf(float f) {
  union { float f; unsigned u; } v; v.f = f;
  unsigned r = v.u + 0x7fffu + ((v.u >> 16) & 1u);   // RNE
  return (short)(r >> 16);
}
__device__ __forceinline__ float b2f(short s) {
  union { float f; unsigned u; } v;
  v.u = ((unsigned)(unsigned short)s) << 16;
  return v.f;
}

// ---------------------------------------------------------------------------
// ONE prep launch, block-range partitioned. Longest-pole range (31-tap fold)
// dispatched FIRST so it doesn't straggle in the tail:
//  blocks [0,4096):      fold feature-conv into W2b[:, 1024:] (inline softmax)
//  blocks [4096,12288):  q fp32 -> Abf bf16 (8 elems/thread)
//  blocks [12288,13312): W1 -> W1b bf16, a/g row-interleaved
//  blocks [13312,13824): W2[:, :1024] -> W2b[:, :1024] bf16
__global__ __launch_bounds__(256) void prep_all(const float* __restrict__ q,
                                                const float* __restrict__ W1,
                                                const float* __restrict__ W2,
                                                const float* __restrict__ wtf,
                                                short* __restrict__ Abf,
                                                short* __restrict__ W1b,
                                                short* __restrict__ W2b) {
  const int bid = blockIdx.x;
  const int tid = threadIdx.x;
  if (bid < 4096) {
    // fold: W2fold[o,j] = sum_k wf[k] * W2[o, 1024 + (j+15-k)]
    int idx = bid * 256 + tid;                    // over 1048576
    int o = idx >> 10, j = idx & 1023;
    float e[KW_], mx = -1e30f, ssum = 0.f;
    #pragma unroll
    for (int k = 0; k < KW_; ++k) mx = fmaxf(mx, wtf[k]);
    #pragma unroll
    for (int k = 0; k < KW_; ++k) { e[k] = __expf(wtf[k] - mx); ssum += e[k]; }
    const float inv = 1.f / ssum;
    const float* base = W2 + (long)o * K2_ + C_;
    float s = 0.f;
    #pragma unroll
    for (int k = 0; k < KW_; ++k) {
      int c = j + 15 - k;
      if (c >= 0 && c < C_) s += e[k] * inv * base[c];
    }
    W2b[(long)o * K2_ + C_ + j] = f2bf(s);
  } else if (bid < 12288) {
    // cvt q: 2M threads x 8 elems
    int idx = (bid - 4096) * 256 + tid;
    const float4* src = (const float4*)q + (long)idx * 2;
    float4 f0 = src[0], f1 = src[1];
    bf16x8 o = { f2bf(f0.x), f2bf(f0.y), f2bf(f0.z), f2bf(f0.w),
                 f2bf(f1.x), f2bf(f1.y), f2bf(f1.z), f2bf(f1.w) };
    *((bf16x8*)Abf + idx) = o;
  } else if (bid < 13312) {
    // W1 interleave: row 2j = W1[j] (a), row 2j+1 = W1[1024+j] (g)
    int idx = (bid - 12288) * 256 + tid;          // over 262144
    int r = idx >> 7;
    int c = (idx & 127) * 8;
    int s = (r & 1) ? (1024 + (r >> 1)) : (r >> 1);
    const float* src = W1 + (long)s * 1024 + c;
    bf16x8 o;
    #pragma unroll
    for (int i = 0; i < 8; ++i) o[i] = f2bf(src[i]);
    *(bf16x8*)(W1b + (long)r * 1024 + c) = o;
  } else {
    // W2 first half copy
    int idx = (bid - 13312) * 256 + tid;          // over 131072
    int o  = idx >> 7;
    int c8 = (idx & 127) * 8;
    const float* src = W2 + (long)o * K2_ + c8;
    bf16x8 v;
    #pragma unroll
    for (int i = 0; i < 8; ++i) v[i] = f2bf(src[i]);
    *(bf16x8*)(W2b + (long)o * K2_ + c8) = v;
  }
}

// ---------------------------------------------------------------------------
// depthwise conv over time: xc[b,t,c] = sum_k w[c%16,k] * x[b,t+k-15,c]
// t-block = 64 -> 1024 blocks (4/CU, 16 waves/CU). Read amp 1.47x.
__global__ __launch_bounds__(256) void conv_t_k(const short* __restrict__ A2in,
                                                const float* __restrict__ wt,
                                                short* __restrict__ A2out) {
  const int tid = threadIdx.x;
  const int t0  = blockIdx.x * 64;
  const int c   = blockIdx.y * 256 + tid;
  const int b   = blockIdx.z;
  const int h   = c & (H_ - 1);

  float wk[KW_];
  {
    const float* src = wt + h * KW_;
    float mx = -1e30f, ssum = 0.f;
    #pragma unroll
    for (int k = 0; k < KW_; ++k) mx = fmaxf(mx, src[k]);
    #pragma unroll
    for (int k = 0; k < KW_; ++k) { wk[k] = __expf(src[k] - mx); ssum += wk[k]; }
    const float inv = 1.f / ssum;
    #pragma unroll
    for (int k = 0; k < KW_; ++k) wk[k] *= inv;
  }

  const long rowbase = ((long)b * T_) * K2_ + C_ + c;
  float win[KW_];
  #pragma unroll
  for (int k = 0; k < 30; ++k) {
    int t = t0 - 15 + k;
    win[k] = (t >= 0 && t < T_) ? b2f(A2in[rowbase + (long)t * K2_]) : 0.f;
  }
  for (int tt = 0; tt < 64; ++tt) {
    int tl = t0 + tt + 15;
    win[30] = (tl < T_) ? b2f(A2in[rowbase + (long)tl * K2_]) : 0.f;
    float s = 0.f;
    #pragma unroll
    for (int k = 0; k < KW_; ++k) s = fmaf(wk[k], win[k], s);
    A2out[((long)b * T_ + t0 + tt) * K2_ + c] = f2bf(s);
    #pragma unroll
    for (int k = 0; k < 30; ++k) win[k] = win[k + 1];
  }
}

// ---------------------------------------------------------------------------
// 128x128 bf16 GEMM = r9 geometry/slots with HALF THE BARRIERS (r17, best):
// per sub-phase {reads; stage; [VMW]; lgkmcnt(0); BAR; prio1; MFMA; prio0}
// -> 4 barriers / 2 K-tiles.
// Safety WITH the per-wave lgkm(0) wall, single barrier:
//  - overwrite: region X's last reader drains its own ds_reads (lgkm0)
//    BEFORE its barrier; the stager issues X's overwrite only AFTER passing
//    that same barrier. Slots: P1 stages A1 (last read prev-P4), P2 stages
//    B0 (last read P1), P3 stages A0 (P2), P4 stages B1 (P3). All safe.
//  - read-readiness: counted VMW + barrier before dependent reads.
//    VMW(2)@P4: outstanding {B0(P2),A0(P3),B1(P4)}=6, retires B0,A0 =
//    next-P1 deps. VMW(2)@P2: outstanding {B1(prev-P4),A1(P1),B0(P2)}=6,
//    retires B1,A1 = P3 deps. Wall cost covered by 4 waves/SIMD +
//    co-resident block (2 blocks/CU).
// Swizzle: byte ^= (row&7)<<4 (128B rows); linear LDS dest + inverse-
// swizzled global source + swizzled read (rule 21). Conflicts = 0.

#define ST_H(GP, GR0, BUFS, REG, KT, HH) do { \
    int d = tid * 16;                  /* byte in 8KB half */ \
    int rr_ = (HH) * 64 + (d >> 7);    /* row in 128-row region */ \
    int scb = (d & 127) ^ ((rr_ & 7) << 4); \
    __builtin_amdgcn_global_load_lds( \
      (GV*)(GP + (long)(GR0 + rr_) * K + (KT) * 64 + (scb >> 1)), \
      (LV*)&lds[(BUFS) + (REG) + (HH) * 4096 + (d >> 1)], 16, 0, 0); \
  } while (0)
#define ST_A(BUFS, KT) do { ST_H(A,  arow0, BUFS, 0,    KT, 0); \
                            ST_H(A,  arow0, BUFS, 0,    KT, 1); } while (0)
#define ST_B(BUFS, KT) do { ST_H(Bw, brow0, BUFS, 8192, KT, 0); \
                            ST_H(Bw, brow0, BUFS, 8192, KT, 1); } while (0)

#define RD_A2(DST, BUFS, MP) do { \
    _Pragma("unroll") \
    for (int mm = 0; mm < 2; ++mm) \
      _Pragma("unroll") \
      for (int kk = 0; kk < 2; ++kk) { \
        int r = wm * 64 + ((MP) * 2 + mm) * 16 + rlane; \
        int byt = (r * 128 + kk * 64 + klb) ^ ((r & 7) << 4); \
        DST[mm * 2 + kk] = *(const bf16x8*)&lds[(BUFS) + (byt >> 1)]; \
      } \
  } while (0)

#define RD_B(DST, BUFS) do { \
    _Pragma("unroll") \
    for (int n = 0; n < 2; ++n) \
      _Pragma("unroll") \
      for (int kk = 0; kk < 2; ++kk) { \
        int r = wn * 32 + n * 16 + rlane; \
        int byt = (r * 128 + kk * 64 + klb) ^ ((r & 7) << 4); \
        DST[n * 2 + kk] = *(const bf16x8*)&lds[(BUFS) + 8192 + (byt >> 1)]; \
      } \
  } while (0)

#define MM(AV, BV, MP) do { \
    _Pragma("unroll") \
    for (int mm = 0; mm < 2; ++mm) \
      _Pragma("unroll") \
      for (int n = 0; n < 2; ++n) \
        _Pragma("unroll") \
        for (int kk = 0; kk < 2; ++kk) \
          acc[2 * (MP) + mm][n] = __builtin_amdgcn_mfma_f32_16x16x32_bf16( \
              AV[mm * 2 + kk], BV[n * 2 + kk], acc[2 * (MP) + mm][n], 0, 0, 0); \
  } while (0)

#define VMW(n_)  asm volatile("s_waitcnt vmcnt(" #n_ ")" ::: "memory")
// single per-phase sync: own-reads drain, barrier, raise prio
#define WALLBAR() do { asm volatile("s_waitcnt lgkmcnt(0)" ::: "memory"); \
                       asm volatile("" ::: "memory"); __builtin_amdgcn_s_barrier(); \
                       __builtin_amdgcn_s_setprio(1); } while (0)
#define PRIO0() __builtin_amdgcn_s_setprio(0)

template<int MODE>
__global__ __launch_bounds__(512, 4) void gemm128(const short* __restrict__ A,
                                                  const short* __restrict__ Bw,
                                                  const float* __restrict__ bias,
                                                  void* __restrict__ Cout,
                                                  int K, int NBN, int ldo) {
  __shared__ short lds[32768];   // 64 KB: 2 bufs x (A 16KB + B 16KB)
  const int tid  = threadIdx.x;
  const int lane = tid & 63;
  const int wave = tid >> 6;
  const int wm = wave >> 2, wn = wave & 3;

  // bijective XCD swizzle (nwg % 8 == 0 for both GEMMs)
  const int nwg = gridDim.x;
  const int wg  = (blockIdx.x & 7) * (nwg >> 3) + (blockIdx.x >> 3);
  const int bm = wg / NBN, bn = wg % NBN;
  const int arow0 = bm * 128, brow0 = bn * 128;

  const int rlane = lane & 15;
  const int klb   = (lane >> 4) * 16;   // byte offset of lane's k-slice

  f32x4 acc[4][2] = {};
  const int nt = K >> 6;                // 64-K tiles (even, >= 4)
  const int ni = nt >> 1;               // iterations of 2 tiles (>= 2)

  bf16x8 aF[4], bA[4], bB[4];

  // prologue: A0,B0 <- t0 (4 loads), B1 <- t1 (2); retire A0,B0, keep B1.
  ST_A(0, 0); ST_B(0, 0);
  ST_B(16384, 1);
  VMW(2);
  asm volatile("" ::: "memory"); __builtin_amdgcn_s_barrier();

  for (int i = 0; i + 1 < ni; ++i) {
    const int kt1 = 2 * i + 1, kt2 = 2 * i + 2, kt3 = 2 * i + 3;
    /*P1*/ RD_B(bA, 0); RD_A2(aF, 0, 0);         ST_A(16384, kt1);          WALLBAR(); MM(aF, bA, 0); PRIO0();
    /*P2*/ RD_A2(aF, 0, 1);                      ST_B(0, kt2);     VMW(2);  WALLBAR(); MM(aF, bA, 1); PRIO0();
    /*P3*/ RD_B(bB, 16384); RD_A2(aF, 16384, 0); ST_A(0, kt2);              WALLBAR(); MM(aF, bB, 0); PRIO0();
    /*P4*/ RD_A2(aF, 16384, 1);                  ST_B(16384, kt3); VMW(2);  WALLBAR(); MM(aF, bB, 1); PRIO0();
  }
  // tail iteration (tiles nt-2 in buf0, nt-1 in buf1): stage A1 only.
  /*P1*/ RD_B(bA, 0); RD_A2(aF, 0, 0);           ST_A(16384, nt - 1);       WALLBAR(); MM(aF, bA, 0); PRIO0();
  /*P2*/ RD_A2(aF, 0, 1);                                           VMW(0); WALLBAR(); MM(aF, bA, 1); PRIO0();
  /*P3*/ RD_B(bB, 16384); RD_A2(aF, 16384, 0);                              WALLBAR(); MM(aF, bB, 0); PRIO0();
  /*P4*/ RD_A2(aF, 16384, 1);
  asm volatile("s_waitcnt lgkmcnt(0)" ::: "memory");
  MM(aF, bB, 1);
  __builtin_amdgcn_s_setprio(0);

  // epilogue: C/D layout col = lane&15, row = (lane>>4)*4 + i
  #pragma unroll
  for (int m = 0; m < 4; ++m) {
    const int r = arow0 + wm * 64 + m * 16 + (lane >> 4) * 4;
    #pragma unroll
    for (int n = 0; n < 2; ++n) {
      const int c = brow0 + wn * 32 + n * 16 + (lane & 15);
      if (MODE == 0) {
        const float bb = bias[c];
        #pragma unroll
        for (int i = 0; i < 4; ++i)
          ((float*)Cout)[(long)(r + i) * ldo + c] = acc[m][n][i] + bb;
      } else {
        // interleaved: even c = a_{c/2}, odd c = g_{c/2}; GLU = a*sigmoid(g)
        const int oc = (c & 1) ? (1024 + (c >> 1)) : (c >> 1);
        const float bb = bias[oc];
        #pragma unroll
        for (int i = 0; i < 4; ++i) {
          float v = acc[m][n][i] + bb;
          float o = __shfl_xor(v, 1);    // partner lane holds the paired col
          if (!(c & 1))
            ((short*)Cout)[(long)(r + i) * ldo + 1024 + (c >> 1)] =
                f2bf(v / (1.f + __expf(-o)));
        }
      }
    }
  }
}

// ---------------------------------------------------------------------------
extern "C" void kernel_launch(void* const* d_in, const int* in_sizes, int n_in,
                              void* d_out, int out_size, void* d_ws, size_t ws_size,
                              hipStream_t stream) {
  const float* q   = (const float*)d_in[0];
  const float* W1  = (const float*)d_in[4];
  const float* b1  = (const float*)d_in[5];
  const float* W2  = (const float*)d_in[6];
  const float* b2  = (const float*)d_in[7];
  const float* wt  = (const float*)d_in[8];
  const float* wtf = (const float*)d_in[9];

  // workspace layout (bf16 as short), ~104 MB total
  short* Abf = (short*)d_ws;                       // 16384x1024
  short* W1b = Abf + (long)M_ * K1_;               // 2048x1024 interleaved
  short* W2b = W1b + (long)N1_ * K1_;              // 1024x2048 (B^T for GEMM2)
  short* A2  = W2b + (long)N2_ * K2_;              // 16384x2048: [xc | x]

  // one prep launch: fold W2 (longest pole, first) + cvt q + cvt W1 + cvt W2
  prep_all<<<13824, 256, 0, stream>>>(q, W1, W2, wtf, Abf, W1b, W2b);

  // GEMM1 + fused GLU: x -> A2[:, 1024:2048]
  gemm128<1><<<(M_ / 128) * (N1_ / 128), 512, 0, stream>>>(
      Abf, W1b, b1, A2, K1_, N1_ / 128, K2_);

  // time depthwise conv (inline per-head softmax) -> A2[:, 0:1024]
  conv_t_k<<<dim3(T_ / 64, C_ / 256, B_), 256, 0, stream>>>(A2, wt, A2);

  // GEMM2: out = A2 @ W2b^T + b2 -> fp32
  gemm128<0><<<(M_ / 128) * (N2_ / 128), 512, 0, stream>>>(
      A2, W2b, b2, d_out, K2_, N2_ / 128, N2_);
}